// Round 1
// baseline (463.898 us; speedup 1.0000x reference)
//
#include <hip/hip_runtime.h>

// db2 analysis filters (already reversed per pytorch_wavelets.prep_filt_afb1d)
#define H00  0.48296291314469025f
#define H01  0.8365163037378079f
#define H02  0.22414386804185735f
#define H03 -0.12940952255092145f

#define H10 -0.12940952255092145f
#define H11 -0.22414386804185735f
#define H12  0.8365163037378079f
#define H13 -0.48296291314469025f

namespace {
constexpr int Bn      = 16;
constexpr int Cn      = 256;
constexpr int HWv     = (128 * 128) / 4;   // 4096 float4 columns per channel plane
constexpr int KPAIRS  = Cn / 2;            // 128 output (lo,hi) pairs
constexpr int KPC     = 32;                // k-pairs per thread (channel chunk)
constexpr int NCHUNK  = KPAIRS / KPC;      // 4 chunks
constexpr unsigned SPATIAL4 = (unsigned)Bn * HWv;  // 65536 float4 columns total
}  // namespace

__global__ __launch_bounds__(256) void dwt_db2_channel_kernel(
    const float4* __restrict__ x, float4* __restrict__ out)
{
    const unsigned tid   = blockIdx.x * 256u + threadIdx.x;
    const unsigned s4    = tid & (SPATIAL4 - 1);   // spatial float4 id (coalesced)
    const unsigned chunk = tid >> 16;              // tid / SPATIAL4 : which k-chunk
    const unsigned b     = s4 / HWv;
    const unsigned hw    = s4 & (HWv - 1);
    const int      k0    = chunk * KPC;

    const float4* __restrict__ xb = x   + (size_t)b * Cn * HWv + hw;
    float4*       __restrict__ ob = out + (size_t)b * Cn * HWv + hw;

    // sliding window over input channels: w0,w1,w2,w3 = x[2k-2 .. 2k+1]
    float4 w0, w1;
    if (k0 == 0) {
        // zero-mode padding: channels -2, -1 are zero
        w0 = make_float4(0.f, 0.f, 0.f, 0.f);
        w1 = w0;
    } else {
        w0 = xb[(size_t)(2 * k0 - 2) * HWv];
        w1 = xb[(size_t)(2 * k0 - 1) * HWv];
    }

#pragma unroll 4
    for (int kk = 0; kk < KPC; ++kk) {
        const int k = k0 + kk;
        const float4 w2 = xb[(size_t)(2 * k)     * HWv];
        const float4 w3 = xb[(size_t)(2 * k + 1) * HWv];

        float4 lo, hi;
        lo.x = H00 * w0.x + H01 * w1.x + H02 * w2.x + H03 * w3.x;
        lo.y = H00 * w0.y + H01 * w1.y + H02 * w2.y + H03 * w3.y;
        lo.z = H00 * w0.z + H01 * w1.z + H02 * w2.z + H03 * w3.z;
        lo.w = H00 * w0.w + H01 * w1.w + H02 * w2.w + H03 * w3.w;

        hi.x = H10 * w0.x + H11 * w1.x + H12 * w2.x + H13 * w3.x;
        hi.y = H10 * w0.y + H11 * w1.y + H12 * w2.y + H13 * w3.y;
        hi.z = H10 * w0.z + H11 * w1.z + H12 * w2.z + H13 * w3.z;
        hi.w = H10 * w0.w + H11 * w1.w + H12 * w2.w + H13 * w3.w;

        ob[(size_t)k * HWv]            = lo;   // lowpass  -> channels [0, 128)
        ob[(size_t)(KPAIRS + k) * HWv] = hi;   // highpass -> channels [128, 256)

        w0 = w2;
        w1 = w3;
    }
}

extern "C" void kernel_launch(void* const* d_in, const int* in_sizes, int n_in,
                              void* d_out, int out_size, void* d_ws, size_t ws_size,
                              hipStream_t stream) {
    (void)in_sizes; (void)n_in; (void)d_ws; (void)ws_size; (void)out_size;
    const float4* x   = (const float4*)d_in[0];
    float4*       out = (float4*)d_out;

    const unsigned total_threads = SPATIAL4 * NCHUNK;  // 262144
    const unsigned block = 256;
    const unsigned grid  = total_threads / block;      // 1024

    dwt_db2_channel_kernel<<<grid, block, 0, stream>>>(x, out);
}

// Round 4
// 420.502 us; speedup vs baseline: 1.1032x; 1.1032x over previous
//
#include <hip/hip_runtime.h>

// db2 analysis filters (already reversed per pytorch_wavelets.prep_filt_afb1d)
#define H00  0.48296291314469025f
#define H01  0.8365163037378079f
#define H02  0.22414386804185735f
#define H03 -0.12940952255092145f

#define H10 -0.12940952255092145f
#define H11 -0.22414386804185735f
#define H12  0.8365163037378079f
#define H13 -0.48296291314469025f

typedef float f4 __attribute__((ext_vector_type(4)));

namespace {
constexpr int Bn      = 16;
constexpr int Cn      = 256;
constexpr int HWv     = (128 * 128) / 4;   // 4096 f4 columns per channel plane
constexpr int KPAIRS  = Cn / 2;            // 128 output (lo,hi) pairs
constexpr int KPC     = 16;                // k-pairs per thread (channel chunk)
constexpr int NCHUNK  = KPAIRS / KPC;      // 8 chunks
constexpr unsigned SPATIAL4 = (unsigned)Bn * HWv;  // 65536 f4 columns total
}  // namespace

__global__ __launch_bounds__(256, 8) void dwt_db2_channel_kernel(
    const f4* __restrict__ x, f4* __restrict__ out)
{
    const unsigned tid   = blockIdx.x * 256u + threadIdx.x;
    const unsigned s4    = tid & (SPATIAL4 - 1);   // spatial f4 id (coalesced)
    const unsigned chunk = tid >> 16;              // which k-chunk (0..7)
    const unsigned b     = s4 / HWv;
    const unsigned hw    = s4 & (HWv - 1);
    const int      k0    = chunk * KPC;

    const f4* __restrict__ xp  = x   + (size_t)b * Cn * HWv + hw
                                     + (size_t)(2 * k0) * HWv;
    f4*       __restrict__ olo = out + (size_t)b * Cn * HWv + hw
                                     + (size_t)k0 * HWv;
    f4*       __restrict__ ohi = olo + (size_t)KPAIRS * HWv;

    // sliding window over input channels: w0,w1 = x[2k-2], x[2k-1]
    f4 w0, w1;
    if (chunk == 0) {
        w0 = (f4){0.f, 0.f, 0.f, 0.f};   // zero-mode padding
        w1 = w0;
    } else {
        w0 = __builtin_nontemporal_load(xp - 2 * HWv);
        w1 = __builtin_nontemporal_load(xp - 1 * HWv);
    }

#pragma unroll 2
    for (int kk = 0; kk < KPC; ++kk) {
        const f4 w2 = __builtin_nontemporal_load(xp);
        const f4 w3 = __builtin_nontemporal_load(xp + HWv);
        xp += 2 * HWv;

        f4 lo = H00 * w0 + H01 * w1 + H02 * w2 + H03 * w3;
        f4 hi = H10 * w0 + H11 * w1 + H12 * w2 + H13 * w3;

        __builtin_nontemporal_store(lo, olo);   // lowpass  -> channels [0, 128)
        __builtin_nontemporal_store(hi, ohi);   // highpass -> channels [128, 256)
        olo += HWv;
        ohi += HWv;

        w0 = w2;
        w1 = w3;
    }
}

extern "C" void kernel_launch(void* const* d_in, const int* in_sizes, int n_in,
                              void* d_out, int out_size, void* d_ws, size_t ws_size,
                              hipStream_t stream) {
    (void)in_sizes; (void)n_in; (void)d_ws; (void)ws_size; (void)out_size;
    const f4* x   = (const f4*)d_in[0];
    f4*       out = (f4*)d_out;

    const unsigned total_threads = SPATIAL4 * NCHUNK;  // 524288
    const unsigned block = 256;
    const unsigned grid  = total_threads / block;      // 2048

    dwt_db2_channel_kernel<<<grid, block, 0, stream>>>(x, out);
}